// Round 12
// baseline (146.784 us; speedup 1.0000x reference)
//
#include <hip/hip_runtime.h>

#define IN_DIM   320
#define POOL_DIM 256
#define HID      128
#define RPB      64             // rows per block (2 waves x 32 rows)
#define NT       128            // threads per block
#define NKC      10             // 320 / 32
#define NSEG     8              // max graph segments per 64-row block

typedef __attribute__((ext_vector_type(8))) short bf16x8;
typedef __attribute__((ext_vector_type(4))) float f32x4;

typedef __attribute__((address_space(1))) const unsigned int guint;
typedef __attribute__((address_space(3))) unsigned int luint;

__device__ __forceinline__ void gl_lds16(const void* g, void* l) {
    __builtin_amdgcn_global_load_lds((guint*)g, (luint*)l, 16, 0, 0);
}

__device__ __forceinline__ unsigned fbits(float f) {
    union { float f; unsigned u; } c; c.f = f; return c.u;
}
__device__ __forceinline__ unsigned pack2(unsigned u0, unsigned u1) {
    return __builtin_amdgcn_perm(u1, u0, 0x07060302u);
}

// split 8 f32 into hi(trunc-bf16) + lo(bf16 of residual)
__device__ __forceinline__ void split8(float4 a, float4 b, bf16x8& hi, bf16x8& lo) {
    float f[8] = { a.x, a.y, a.z, a.w, b.x, b.y, b.z, b.w };
    unsigned hu[8], lu[8];
#pragma unroll
    for (int i = 0; i < 8; ++i) {
        unsigned u = fbits(f[i]);
        hu[i] = u;
        float hif = __builtin_bit_cast(float, u & 0xffff0000u);
        lu[i] = fbits(f[i] - hif);
    }
    int4 hp, lp;
    hp.x = pack2(hu[0], hu[1]); hp.y = pack2(hu[2], hu[3]);
    hp.z = pack2(hu[4], hu[5]); hp.w = pack2(hu[6], hu[7]);
    lp.x = pack2(lu[0], lu[1]); lp.y = pack2(lu[2], lu[3]);
    lp.z = pack2(lu[4], lu[5]); lp.w = pack2(lu[6], lu[7]);
    hi = __builtin_bit_cast(bf16x8, hp);
    lo = __builtin_bit_cast(bf16x8, lp);
}

// ---------------------------------------------------------------------------
// One-time: pack W1 into MFMA B-fragment order, split hi/lo (frag-linear):
//   Wpk[((kc*16 + ht*2 + s)*64 + lane)*8 + j]
// ---------------------------------------------------------------------------
__global__ __launch_bounds__(256) void pack_w1_kernel(
    const float* __restrict__ W1, ushort* __restrict__ Wpk)
{
    const int i = blockIdx.x * 256 + threadIdx.x;
    if (i >= NKC * 8 * 2 * 64) return;
    const int kc   = i >> 10;
    const int r    = i & 1023;
    const int ht   = r >> 7;
    const int r2   = r & 127;
    const int s    = r2 >> 6;
    const int lane = r2 & 63;
    const int h    = ht * 16 + (lane & 15);
    const int k0   = kc * 32 + (lane >> 4) * 8;

    ushort v[8];
#pragma unroll
    for (int j = 0; j < 8; ++j) {
        const float f = W1[(size_t)h * IN_DIM + k0 + j];
        const unsigned u = fbits(f);
        if (s == 0) {
            v[j] = (ushort)(u >> 16);
        } else {
            const float hif = __builtin_bit_cast(float, u & 0xffff0000u);
            v[j] = (ushort)(fbits(f - hif) >> 16);
        }
    }
    ushort* dst = Wpk + (size_t)i * 8;
#pragma unroll
    for (int j = 0; j < 8; ++j) dst[j] = v[j];
}

// ---------------------------------------------------------------------------
// Fused kernel: 64 rows/block, 2 waves.  z chunks (8 KB each) are DMA'd into
// a PERSISTENT 8-slot LDS region (zkeep, 64 KB = cols 0..255) -- issued all
// upfront so HBM stays saturated; kc order {8,9,0..7} lets chunks kc8/kc9
// (cols 256-319) transiently borrow slots 6,7 before kc6/kc7 refill them.
// W streams through a single 16 KB LDS buffer (L2-hot, refill hides under
// MFMA phase).  Plain __syncthreads drains are cheap: only W refills are
// freshly issued.  After scores: block max/sumexp, single-wave ballot
// segment scan of sorted batch_index, and per-segment weighted partial sums
// read FROM LDS (no z re-read).  P[b][s][rg][64] f32x4 + meta[b][s]=gid.
// ---------------------------------------------------------------------------
__global__ __launch_bounds__(NT) void attn_fused(
    const float* __restrict__ z, const ushort* __restrict__ Wpk,
    const float* __restrict__ b1, const float* __restrict__ W2,
    const float* __restrict__ b2, const int* __restrict__ bidx,
    float* __restrict__ bmax, float* __restrict__ bsum,
    float* __restrict__ P, int* __restrict__ meta, int N)
{
    __shared__ f32x4 zkeep4[8 * 512];   // 64 KB: slot k holds chunk kc=k
    __shared__ f32x4 wbuf4[1024];       // 16 KB single W buffer
    // epilogue state aliases into wbuf (W reads finished by then):
    float* sblk    = (float*)wbuf4;                      // 64 f
    int*   seg_s0  = (int*)((char*)wbuf4 + 256);         // 9 ints
    int*   seg_gid = (int*)((char*)wbuf4 + 528);         // 8 ints
    float* shm_m   = (float*)((char*)wbuf4 + 784);
    int*   shm_ns  = (int*)((char*)wbuf4 + 788);

    const int tid  = threadIdx.x;
    const int wid  = tid >> 6;           // 0..1
    const int lane = tid & 63;
    const int lm   = lane & 15;
    const int lg   = lane >> 4;
    const int bk   = blockIdx.x;
    const int r0   = bk * RPB;

    // per-thread z DMA source bases: chunk slot s = j*NT+tid, row = s>>3,
    // source quad = (s&7) ^ (row&7)  (XOR on GLOBAL source; LDS dest linear)
    const char* zsrc[4];
#pragma unroll
    for (int j = 0; j < 4; ++j) {
        const int s   = j * NT + tid;
        const int row = s >> 3;
        const int q   = (s & 7) ^ (row & 7);
        int gr = r0 + row; if (gr > N - 1) gr = N - 1;
        zsrc[j] = (const char*)z + (size_t)gr * (IN_DIM * 4) + q * 16;
    }

    #define STAGE_ZC(kc_, sl_)                                                \
        { char* dst = (char*)zkeep4 + (sl_) * 8192;                           \
          _Pragma("unroll")                                                   \
          for (int j = 0; j < 4; ++j) {                                       \
              const int o = (j * NT + tid) * 16;                              \
              gl_lds16(zsrc[j] + (kc_) * 128, dst + o);                       \
          } }

    #define STAGE_W(kc_)                                                      \
        { const char* src = (const char*)Wpk + (size_t)(kc_) * 16384;         \
          char* dst = (char*)wbuf4;                                           \
          _Pragma("unroll")                                                   \
          for (int j = 0; j < 8; ++j) {                                       \
              const int o = (j * NT + tid) * 16;                              \
              gl_lds16(src + o, dst + o);                                     \
          } }

    // prologue: iter0's needs first, then the rest of z upfront
    STAGE_ZC(8, 6);
    STAGE_W(8);
    STAGE_ZC(9, 7);
    STAGE_ZC(0, 0); STAGE_ZC(1, 1); STAGE_ZC(2, 2);
    STAGE_ZC(3, 3); STAGE_ZC(4, 4); STAGE_ZC(5, 5);

    f32x4 acc[2][8];
#pragma unroll
    for (int rt = 0; rt < 2; ++rt)
#pragma unroll
        for (int ht = 0; ht < 8; ++ht) acc[rt][ht] = (f32x4){0.f, 0.f, 0.f, 0.f};

    // loop-invariant z frag read indices (within a slot): rows, swizzled quads
    const int lr0 = wid * 32 + lm;
    const int lr1 = lr0 + 16;
    const int j00 = lr0 * 8 + ((2 * lg)     ^ (lr0 & 7));
    const int j01 = lr0 * 8 + ((2 * lg + 1) ^ (lr0 & 7));
    const int j10 = lr1 * 8 + ((2 * lg)     ^ (lr1 & 7));
    const int j11 = lr1 * 8 + ((2 * lg + 1) ^ (lr1 & 7));

    const int ord_kc[NKC] = {8, 9, 0, 1, 2, 3, 4, 5, 6, 7};
    const int ord_sl[NKC] = {6, 7, 0, 1, 2, 3, 4, 5, 6, 7};

#pragma unroll
    for (int t = 0; t < NKC; ++t) {
        __syncthreads();   // sync#1: all outstanding DMAs landed

        // read W frags + z frags into registers
        const char* wb_base = (const char*)wbuf4 + lane * 16;
        bf16x8 bh[8], bl[8];
#pragma unroll
        for (int ht = 0; ht < 8; ++ht) {
            bh[ht] = *(const bf16x8*)(wb_base + ht * 2048);
            bl[ht] = *(const bf16x8*)(wb_base + ht * 2048 + 1024);
        }
        const float4* zb = (const float4*)&zkeep4[ord_sl[t] * 512];
        const float4 x0 = zb[j00];
        const float4 x1 = zb[j01];
        const float4 y0 = zb[j10];
        const float4 y1 = zb[j11];

        __syncthreads();   // sync#2: reads done -> wbuf / slots reusable

        if (t + 1 < NKC) STAGE_W(ord_kc[t + 1]);
        if (t == 0) STAGE_ZC(6, 6);     // slot6 readers (kc8) done
        if (t == 1) STAGE_ZC(7, 7);     // slot7 readers (kc9) done

        bf16x8 a0h, a0l, a1h, a1l;
        split8(x0, x1, a0h, a0l);
        split8(y0, y1, a1h, a1l);
#pragma unroll
        for (int ht = 0; ht < 8; ++ht) {
            acc[0][ht] = __builtin_amdgcn_mfma_f32_16x16x32_bf16(a0h, bh[ht], acc[0][ht], 0, 0, 0);
            acc[0][ht] = __builtin_amdgcn_mfma_f32_16x16x32_bf16(a0l, bh[ht], acc[0][ht], 0, 0, 0);
            acc[0][ht] = __builtin_amdgcn_mfma_f32_16x16x32_bf16(a0h, bl[ht], acc[0][ht], 0, 0, 0);
            acc[1][ht] = __builtin_amdgcn_mfma_f32_16x16x32_bf16(a1h, bh[ht], acc[1][ht], 0, 0, 0);
            acc[1][ht] = __builtin_amdgcn_mfma_f32_16x16x32_bf16(a1l, bh[ht], acc[1][ht], 0, 0, 0);
            acc[1][ht] = __builtin_amdgcn_mfma_f32_16x16x32_bf16(a1h, bl[ht], acc[1][ht], 0, 0, 0);
        }
    }

    // ---- scores: relu + dot(W2) per lane-col, reduce over 16 cols
    float b1v[8], w2v[8];
#pragma unroll
    for (int ht = 0; ht < 8; ++ht) {
        b1v[ht] = b1[ht * 16 + lm];
        w2v[ht] = W2[ht * 16 + lm];
    }
    const float b2v = b2[0];

#pragma unroll
    for (int rt = 0; rt < 2; ++rt) {
#pragma unroll
        for (int reg = 0; reg < 4; ++reg) {
            float s = 0.f;
#pragma unroll
            for (int ht = 0; ht < 8; ++ht)
                s += fmaxf(acc[rt][ht][reg] + b1v[ht], 0.f) * w2v[ht];
            s += __shfl_xor(s, 1);
            s += __shfl_xor(s, 2);
            s += __shfl_xor(s, 4);
            s += __shfl_xor(s, 8);
            s += b2v;
            if (lm == 0) {
                const int rloc = wid * 32 + rt * 16 + lg * 4 + reg;
                sblk[rloc] = s;     // N % 64 == 0: all rows valid
            }
        }
    }
    __syncthreads();

    // ---- wave 0: block (max, sum-exp) + segment scan of sorted batch_index
    if (tid < 64) {
        const float v = sblk[tid];
        float m = v;
#pragma unroll
        for (int d = 1; d < 64; d <<= 1) m = fmaxf(m, __shfl_xor(m, d, 64));
        float e = __expf(v - m);
        float es = e;
#pragma unroll
        for (int d = 1; d < 64; d <<= 1) es += __shfl_xor(es, d, 64);

        const int g    = bidx[r0 + tid];
        const int prev = __shfl_up(g, 1);
        const int flag = (tid == 0) || (g != prev);
        const unsigned long long mask = __ballot(flag);
        const int idx = (int)__popcll(mask & ((1ull << tid) - 1ull));
        const int ns  = (int)__popcll(mask);
        if (flag) { seg_s0[idx] = tid; seg_gid[idx] = g; }
        if (tid == 0) {
            bmax[bk] = m; bsum[bk] = es;
            shm_m[0] = m; shm_ns[0] = ns;
            seg_s0[ns] = RPB;
        }
    }
    __syncthreads();

    // ---- per-segment weighted partial sums from LDS (no z re-read)
    const float mb   = shm_m[0];
    const int   nseg = shm_ns[0];
    const int   rg   = wid;             // row parity group 0/1
    const int   kcp  = lane >> 3;       // chunk for this col4
    const int   qp   = lane & 7;
    f32x4* P4 = (f32x4*)P;

#pragma unroll
    for (int s = 0; s < NSEG; ++s) {
        if (s >= nseg) break;
        const int rs = seg_s0[s];
        const int re = seg_s0[s + 1];
        f32x4 a = (f32x4){0.f, 0.f, 0.f, 0.f};
        for (int row = rs + rg; row < re; row += 2) {
            const float w = __expf(sblk[row] - mb);
            a += w * zkeep4[kcp * 512 + row * 8 + (qp ^ (row & 7))];
        }
        P4[(((size_t)bk * NSEG + s) * 2 + rg) * 64 + lane] = a;
    }
    if (tid < NSEG)
        meta[bk * NSEG + tid] = (tid < nseg) ? seg_gid[tid] : -1;
}

// ---------------------------------------------------------------------------
// combine per-block (max, sumexp) -> global max & softmax denom
// ---------------------------------------------------------------------------
__global__ __launch_bounds__(256) void softmax_reduce_kernel(
    const float* __restrict__ bmax, const float* __restrict__ bsum,
    float* __restrict__ red, int nb)
{
    __shared__ float sm[4];
    __shared__ float ss[4];
    const int tid = threadIdx.x;

    float m = -1e30f;
    for (int i = tid; i < nb; i += 256) m = fmaxf(m, bmax[i]);
#pragma unroll
    for (int d = 1; d < 64; d <<= 1) m = fmaxf(m, __shfl_xor(m, d, 64));
    if ((tid & 63) == 0) sm[tid >> 6] = m;
    __syncthreads();
    const float gmax = fmaxf(fmaxf(sm[0], sm[1]), fmaxf(sm[2], sm[3]));

    float s = 0.f;
    for (int i = tid; i < nb; i += 256) s += bsum[i] * __expf(bmax[i] - gmax);
#pragma unroll
    for (int d = 1; d < 64; d <<= 1) s += __shfl_xor(s, d, 64);
    if ((tid & 63) == 0) ss[tid >> 6] = s;
    __syncthreads();
    if (tid == 0) {
        red[0] = gmax;
        red[1] = ss[0] + ss[1] + ss[2] + ss[3];
    }
}

// ---------------------------------------------------------------------------
// Per-graph combine of block partials:
// out[g] = (1/den/count) * sum_{b overlapping g} exp(m_b - gmax) * P_b[g]
// ---------------------------------------------------------------------------
__device__ __forceinline__ int lower_bound(const int* __restrict__ a, int n, int key)
{
    int lo = 0, hi = n;
    while (lo < hi) {
        int mid = (lo + hi) >> 1;
        if (a[mid] < key) lo = mid + 1; else hi = mid;
    }
    return lo;
}

__global__ __launch_bounds__(64) void combine_kernel(
    const int* __restrict__ bidx, const float* __restrict__ bmax,
    const float* __restrict__ red, const float* __restrict__ P,
    const int* __restrict__ meta, float* __restrict__ out, int N)
{
    const int g    = blockIdx.x;
    const int lane = threadIdx.x;

    const int start = lower_bound(bidx, N, g);
    const int end   = lower_bound(bidx, N, g + 1);
    const float gmax    = red[0];
    const float inv_den = 1.0f / red[1];

    f32x4 a = (f32x4){0.f, 0.f, 0.f, 0.f};
    if (end > start) {
        const int b0 = start >> 6;
        const int b1 = (end - 1) >> 6;
        const f32x4* P4 = (const f32x4*)P;
        for (int b = b0; b <= b1; ++b) {
            int s = -1;
#pragma unroll
            for (int k = 0; k < NSEG; ++k)
                if (meta[b * NSEG + k] == g) s = k;
            if (s < 0) continue;
            const size_t base = (((size_t)b * NSEG + s) * 2) * 64 + lane;
            const f32x4 t2 = P4[base] + P4[base + 64];
            a += __expf(bmax[b] - gmax) * t2;
        }
    }
    const int cnt = end - start;
    const float sc = inv_den / fmaxf((float)cnt, 1.0f);
    ((f32x4*)out)[(size_t)g * 64 + lane] = a * sc;
}

// ---------------------------------------------------------------------------
extern "C" void kernel_launch(void* const* d_in, const int* in_sizes, int n_in,
                              void* d_out, int out_size, void* d_ws, size_t ws_size,
                              hipStream_t stream)
{
    const float* z    = (const float*)d_in[0];
    const int*   bidx = (const int*)  d_in[1];
    const float* W1   = (const float*)d_in[2];
    const float* b1   = (const float*)d_in[3];
    const float* W2   = (const float*)d_in[4];
    const float* b2   = (const float*)d_in[5];
    float*       out  = (float*)d_out;

    const int N  = in_sizes[0] / IN_DIM;       // 200000
    const int G  = out_size / POOL_DIM;        // 2000
    const int nb = (N + RPB - 1) / RPB;        // 3125 (<= 3200 padded)

    // workspace layout
    float*  bmax = (float*)d_ws;                        // 3200
    float*  bsum = bmax + 3200;                         // 3200
    float*  red  = bsum + 3200;                         // 16
    int*    meta = (int*)(red + 16);                    // 3200*NSEG ints
    float*  P    = (float*)(meta + 3200 * NSEG);        // 3200*NSEG*2*256 f
    ushort* Wpk  = (ushort*)(P + (size_t)3200 * NSEG * 2 * 256);  // 160 KB

    pack_w1_kernel<<<(NKC * 8 * 2 * 64 + 255) / 256, 256, 0, stream>>>(W1, Wpk);
    attn_fused<<<nb, NT, 0, stream>>>(z, Wpk, b1, W2, b2, bidx,
                                      bmax, bsum, P, meta, N);
    softmax_reduce_kernel<<<1, 256, 0, stream>>>(bmax, bsum, red, nb);
    combine_kernel<<<G, 64, 0, stream>>>(bidx, bmax, red, P, meta, out, N);
}

// Round 13
// 136.022 us; speedup vs baseline: 1.0791x; 1.0791x over previous
//
#include <hip/hip_runtime.h>

#define IN_DIM   320
#define POOL_DIM 256
#define HID      128
#define RPB      64             // rows per block (4 waves x 16 rows)
#define NT       256            // threads per block
#define NKC      10             // 320 / 32
#define NSEG     8              // max graph segments per 64-row block

typedef __attribute__((ext_vector_type(8))) short bf16x8;
typedef __attribute__((ext_vector_type(4))) float f32x4;

typedef __attribute__((address_space(1))) const unsigned int guint;
typedef __attribute__((address_space(3))) unsigned int luint;

__device__ __forceinline__ void gl_lds16(const void* g, void* l) {
    __builtin_amdgcn_global_load_lds((guint*)g, (luint*)l, 16, 0, 0);
}

__device__ __forceinline__ unsigned fbits(float f) {
    union { float f; unsigned u; } c; c.f = f; return c.u;
}
__device__ __forceinline__ unsigned pack2(unsigned u0, unsigned u1) {
    return __builtin_amdgcn_perm(u1, u0, 0x07060302u);
}

// split 8 f32 into hi(trunc-bf16) + lo(bf16 of residual)
__device__ __forceinline__ void split8(float4 a, float4 b, bf16x8& hi, bf16x8& lo) {
    float f[8] = { a.x, a.y, a.z, a.w, b.x, b.y, b.z, b.w };
    unsigned hu[8], lu[8];
#pragma unroll
    for (int i = 0; i < 8; ++i) {
        unsigned u = fbits(f[i]);
        hu[i] = u;
        float hif = __builtin_bit_cast(float, u & 0xffff0000u);
        lu[i] = fbits(f[i] - hif);
    }
    int4 hp, lp;
    hp.x = pack2(hu[0], hu[1]); hp.y = pack2(hu[2], hu[3]);
    hp.z = pack2(hu[4], hu[5]); hp.w = pack2(hu[6], hu[7]);
    lp.x = pack2(lu[0], lu[1]); lp.y = pack2(lu[2], lu[3]);
    lp.z = pack2(lu[4], lu[5]); lp.w = pack2(lu[6], lu[7]);
    hi = __builtin_bit_cast(bf16x8, hp);
    lo = __builtin_bit_cast(bf16x8, lp);
}

// ---------------------------------------------------------------------------
// One-time: pack W1 into MFMA B-fragment order, split hi/lo (frag-linear):
//   Wpk[((kc*16 + ht*2 + s)*64 + lane)*8 + j]
// ---------------------------------------------------------------------------
__global__ __launch_bounds__(256) void pack_w1_kernel(
    const float* __restrict__ W1, ushort* __restrict__ Wpk)
{
    const int i = blockIdx.x * 256 + threadIdx.x;
    if (i >= NKC * 8 * 2 * 64) return;
    const int kc   = i >> 10;
    const int r    = i & 1023;
    const int ht   = r >> 7;
    const int r2   = r & 127;
    const int s    = r2 >> 6;
    const int lane = r2 & 63;
    const int h    = ht * 16 + (lane & 15);
    const int k0   = kc * 32 + (lane >> 4) * 8;

    ushort v[8];
#pragma unroll
    for (int j = 0; j < 8; ++j) {
        const float f = W1[(size_t)h * IN_DIM + k0 + j];
        const unsigned u = fbits(f);
        if (s == 0) {
            v[j] = (ushort)(u >> 16);
        } else {
            const float hif = __builtin_bit_cast(float, u & 0xffff0000u);
            v[j] = (ushort)(fbits(f - hif) >> 16);
        }
    }
    ushort* dst = Wpk + (size_t)i * 8;
#pragma unroll
    for (int j = 0; j < 8; ++j) dst[j] = v[j];
}

// ---------------------------------------------------------------------------
// Fused kernel, 4 waves x 16 rows.  z chunks (8 KB) DMA'd into a PERSISTENT
// 8-slot LDS region (64 KB = cols 0..255), all issued upfront; kc order
// {8,9,0..7} lets chunks 8/9 (cols 256-319) borrow slots 6,7 before chunks
// 6/7 refill them.  W frags live in REGISTERS, double-buffered (coalesced
// frag-packed loads, prefetched one iter ahead -> L2 latency off critical
// path).  Explicit counted vmcnt only at iters 0,1 (and free vmcnt(0) at
// 8,9); iters 2..7 are guaranteed by the compiler's own W-frag register
// waits (issued after all prologue z DMAs) + the per-iter barrier.
// Epilogue: scores -> block max/sumexp -> ballot segment scan -> per-segment
// weighted partial sums read FROM LDS (no z re-read).
// ---------------------------------------------------------------------------
__global__ __launch_bounds__(NT) void attn_fused(
    const float* __restrict__ z, const ushort* __restrict__ Wpk,
    const float* __restrict__ b1, const float* __restrict__ W2,
    const float* __restrict__ b2, const int* __restrict__ bidx,
    float* __restrict__ bmax, float* __restrict__ bsum,
    float* __restrict__ P, int* __restrict__ meta, int N)
{
    __shared__ f32x4 zkeep4[8 * 512];   // 64 KB: slot k holds chunk kc=k
    __shared__ float sblk[RPB];
    __shared__ int   seg_s0[NSEG + 1];
    __shared__ int   seg_gid[NSEG];
    __shared__ float shm_m[1];
    __shared__ int   shm_ns[1];

    const int tid  = threadIdx.x;
    const int wv   = tid >> 6;           // wave 0..3 -> m-tile
    const int lane = tid & 63;
    const int lm   = lane & 15;
    const int lg   = lane >> 4;
    const int bk   = blockIdx.x;
    const int r0   = bk * RPB;

    // ---- prologue register loads FIRST (in-order vmcnt completion means
    //      later counted waits on the DMAs are unaffected by these) ----
    float b1v[8], w2v[8];
#pragma unroll
    for (int ht = 0; ht < 8; ++ht) {
        b1v[ht] = b1[ht * 16 + lm];
        w2v[ht] = W2[ht * 16 + lm];
    }
    const float b2v = b2[0];

    const ushort* wp = Wpk + (size_t)lane * 8;
    #define LOADW(KC, BH, BL)                                                 \
        _Pragma("unroll")                                                     \
        for (int ht = 0; ht < 8; ++ht) {                                      \
            BH[ht] = *(const bf16x8*)(wp + (size_t)((KC)*16 + ht*2) * 512);   \
            BL[ht] = *(const bf16x8*)(wp + (size_t)((KC)*16 + ht*2 + 1) * 512); \
        }

    bf16x8 bhA[8], blA[8], bhB[8], blB[8];
    LOADW(8, bhA, blA);                  // iter0 uses kc=8

    __builtin_amdgcn_sched_barrier(0);

    // ---- z DMA: 8 KB/chunk = 2 gl_lds16 per thread; swizzle on the GLOBAL
    //      source quad (LDS dest linear) ----
    const char* zsrc[2];
#pragma unroll
    for (int j = 0; j < 2; ++j) {
        const int s   = j * 256 + tid;
        const int row = s >> 3;
        const int q   = (s & 7) ^ (row & 7);
        int gr = r0 + row; if (gr > N - 1) gr = N - 1;
        zsrc[j] = (const char*)z + (size_t)gr * (IN_DIM * 4) + q * 16;
    }

    #define STAGE_ZC(kc_, sl_)                                                \
        { char* dst = (char*)zkeep4 + (sl_) * 8192;                           \
          _Pragma("unroll")                                                   \
          for (int j = 0; j < 2; ++j) {                                       \
              const int o = (j * 256 + tid) * 16;                             \
              gl_lds16(zsrc[j] + (kc_) * 128, dst + o);                       \
          } }

    // issue order matters for the counted waits below:
    STAGE_ZC(8, 6);                      // 2 instrs  (iter0)
    STAGE_ZC(9, 7);                      // 2         (iter1)
    STAGE_ZC(0, 0); STAGE_ZC(1, 1); STAGE_ZC(2, 2);
    STAGE_ZC(3, 3); STAGE_ZC(4, 4); STAGE_ZC(5, 5);   // 12
    __builtin_amdgcn_sched_barrier(0);

    // wait z8 (leave z9 + z0..z5 = 14 DMAs in flight), publish to all waves
    asm volatile("s_waitcnt vmcnt(14)" ::: "memory");
    __builtin_amdgcn_sched_barrier(0);
    __builtin_amdgcn_s_barrier();
    __builtin_amdgcn_sched_barrier(0);

    f32x4 acc[8];
#pragma unroll
    for (int ht = 0; ht < 8; ++ht) acc[ht] = (f32x4){0.f, 0.f, 0.f, 0.f};

    // loop-invariant z frag read indices (16 rows per wave)
    const int lr  = wv * 16 + lm;
    const int jj0 = lr * 8 + ((2 * lg)     ^ (lr & 7));
    const int jj1 = lr * 8 + ((2 * lg + 1) ^ (lr & 7));

    const int ord_sl[NKC] = {6, 7, 0, 1, 2, 3, 4, 5, 6, 7};
    const int ord_kc[NKC] = {8, 9, 0, 1, 2, 3, 4, 5, 6, 7};

    #define MFMA24(BH, BL)                                                    \
        _Pragma("unroll")                                                     \
        for (int ht = 0; ht < 8; ++ht) {                                      \
            acc[ht] = __builtin_amdgcn_mfma_f32_16x16x32_bf16(ah, BH[ht], acc[ht], 0, 0, 0); \
            acc[ht] = __builtin_amdgcn_mfma_f32_16x16x32_bf16(al, BH[ht], acc[ht], 0, 0, 0); \
            acc[ht] = __builtin_amdgcn_mfma_f32_16x16x32_bf16(ah, BL[ht], acc[ht], 0, 0, 0); \
        }

#pragma unroll
    for (int t = 0; t < NKC; ++t) {
        if (t == 1) { asm volatile("s_waitcnt vmcnt(2)" ::: "memory"); }  // z9 in; z6 may fly
        if (t >= 8) { asm volatile("s_waitcnt vmcnt(0)" ::: "memory"); }  // slots 6/7 (free)
        if (t > 0) {
            __builtin_amdgcn_sched_barrier(0);
            __builtin_amdgcn_s_barrier();
            __builtin_amdgcn_sched_barrier(0);
        }

        const float4* zb = (const float4*)&zkeep4[ord_sl[t] * 512];
        const float4 x0 = zb[jj0];
        const float4 x1 = zb[jj1];
        bf16x8 ah, al;
        split8(x0, x1, ah, al);

        if ((t & 1) == 0) {
            MFMA24(bhA, blA);
            if (t + 1 < NKC) LOADW(ord_kc[t + 1], bhB, blB);
        } else {
            MFMA24(bhB, blB);
            if (t + 1 < NKC) LOADW(ord_kc[t + 1], bhA, blA);
        }

        if (t == 0 || t == 1) {
            // all waves done reading the borrowed slot -> restage it
            __builtin_amdgcn_sched_barrier(0);
            __builtin_amdgcn_s_barrier();
            __builtin_amdgcn_sched_barrier(0);
            if (t == 0) { STAGE_ZC(6, 6); }
            else        { STAGE_ZC(7, 7); }
            __builtin_amdgcn_sched_barrier(0);
        }
    }

    // ---- scores: relu + dot(W2), reduce over 16 cols -> sblk
#pragma unroll
    for (int reg = 0; reg < 4; ++reg) {
        float s = 0.f;
#pragma unroll
        for (int ht = 0; ht < 8; ++ht)
            s += fmaxf(acc[ht][reg] + b1v[ht], 0.f) * w2v[ht];
        s += __shfl_xor(s, 1);
        s += __shfl_xor(s, 2);
        s += __shfl_xor(s, 4);
        s += __shfl_xor(s, 8);
        s += b2v;
        if (lm == 0) sblk[wv * 16 + lg * 4 + reg] = s;   // N%64==0: all valid
    }
    __syncthreads();

    // ---- wave 0: block (max, sum-exp) + segment scan of sorted batch_index
    if (tid < 64) {
        const float v = sblk[tid];
        float m = v;
#pragma unroll
        for (int d = 1; d < 64; d <<= 1) m = fmaxf(m, __shfl_xor(m, d, 64));
        float e = __expf(v - m);
        float es = e;
#pragma unroll
        for (int d = 1; d < 64; d <<= 1) es += __shfl_xor(es, d, 64);

        const int g    = bidx[r0 + tid];
        const int prev = __shfl_up(g, 1);
        const int flag = (tid == 0) || (g != prev);
        const unsigned long long mask = __ballot(flag);
        const int idx = (int)__popcll(mask & ((1ull << tid) - 1ull));
        const int ns  = (int)__popcll(mask);
        if (flag) { seg_s0[idx] = tid; seg_gid[idx] = g; }
        if (tid == 0) {
            bmax[bk] = m; bsum[bk] = es;
            shm_m[0] = m; shm_ns[0] = ns;
            seg_s0[ns] = RPB;
        }
    }
    __syncthreads();

    // ---- per-segment weighted partial sums from LDS (no z re-read)
    const float mb   = shm_m[0];
    const int   nseg = shm_ns[0];
    const int   rg   = tid >> 6;        // row-group 0..3
    const int   kcp  = lane >> 3;       // chunk for this col4
    const int   qp   = lane & 7;
    f32x4* P4 = (f32x4*)P;

#pragma unroll
    for (int s = 0; s < NSEG; ++s) {
        if (s >= nseg) break;
        const int rs = seg_s0[s];
        const int re = seg_s0[s + 1];
        f32x4 a = (f32x4){0.f, 0.f, 0.f, 0.f};
        for (int row = rs + rg; row < re; row += 4) {
            const float w = __expf(sblk[row] - mb);
            a += w * zkeep4[kcp * 512 + row * 8 + (qp ^ (row & 7))];
        }
        P4[(((size_t)bk * NSEG + s) * 4 + rg) * 64 + lane] = a;
    }
    if (tid < NSEG)
        meta[bk * NSEG + tid] = (tid < nseg) ? seg_gid[tid] : -1;
}

// ---------------------------------------------------------------------------
// combine per-block (max, sumexp) -> global max & softmax denom
// ---------------------------------------------------------------------------
__global__ __launch_bounds__(256) void softmax_reduce_kernel(
    const float* __restrict__ bmax, const float* __restrict__ bsum,
    float* __restrict__ red, int nb)
{
    __shared__ float sm[4];
    __shared__ float ss[4];
    const int tid = threadIdx.x;

    float m = -1e30f;
    for (int i = tid; i < nb; i += 256) m = fmaxf(m, bmax[i]);
#pragma unroll
    for (int d = 1; d < 64; d <<= 1) m = fmaxf(m, __shfl_xor(m, d, 64));
    if ((tid & 63) == 0) sm[tid >> 6] = m;
    __syncthreads();
    const float gmax = fmaxf(fmaxf(sm[0], sm[1]), fmaxf(sm[2], sm[3]));

    float s = 0.f;
    for (int i = tid; i < nb; i += 256) s += bsum[i] * __expf(bmax[i] - gmax);
#pragma unroll
    for (int d = 1; d < 64; d <<= 1) s += __shfl_xor(s, d, 64);
    if ((tid & 63) == 0) ss[tid >> 6] = s;
    __syncthreads();
    if (tid == 0) {
        red[0] = gmax;
        red[1] = ss[0] + ss[1] + ss[2] + ss[3];
    }
}

// ---------------------------------------------------------------------------
// Per-graph combine of block partials:
// out[g] = (1/den/count) * sum_{b overlapping g} exp(m_b - gmax) * P_b[g]
// ---------------------------------------------------------------------------
__device__ __forceinline__ int lower_bound(const int* __restrict__ a, int n, int key)
{
    int lo = 0, hi = n;
    while (lo < hi) {
        int mid = (lo + hi) >> 1;
        if (a[mid] < key) lo = mid + 1; else hi = mid;
    }
    return lo;
}

__global__ __launch_bounds__(64) void combine_kernel(
    const int* __restrict__ bidx, const float* __restrict__ bmax,
    const float* __restrict__ red, const float* __restrict__ P,
    const int* __restrict__ meta, float* __restrict__ out, int N)
{
    const int g    = blockIdx.x;
    const int lane = threadIdx.x;

    const int start = lower_bound(bidx, N, g);
    const int end   = lower_bound(bidx, N, g + 1);
    const float gmax    = red[0];
    const float inv_den = 1.0f / red[1];

    f32x4 a = (f32x4){0.f, 0.f, 0.f, 0.f};
    if (end > start) {
        const int b0 = start >> 6;
        const int b1 = (end - 1) >> 6;
        const f32x4* P4 = (const f32x4*)P;
        for (int b = b0; b <= b1; ++b) {
            int s = -1;
#pragma unroll
            for (int k = 0; k < NSEG; ++k)
                if (meta[b * NSEG + k] == g) s = k;
            if (s < 0) continue;
            const size_t base = (((size_t)b * NSEG + s) * 4) * 64 + lane;
            const f32x4 t2 = (P4[base] + P4[base + 64]) +
                             (P4[base + 128] + P4[base + 192]);
            a += __expf(bmax[b] - gmax) * t2;
        }
    }
    const int cnt = end - start;
    const float sc = inv_den / fmaxf((float)cnt, 1.0f);
    ((f32x4*)out)[(size_t)g * 64 + lane] = a * sc;
}

// ---------------------------------------------------------------------------
extern "C" void kernel_launch(void* const* d_in, const int* in_sizes, int n_in,
                              void* d_out, int out_size, void* d_ws, size_t ws_size,
                              hipStream_t stream)
{
    const float* z    = (const float*)d_in[0];
    const int*   bidx = (const int*)  d_in[1];
    const float* W1   = (const float*)d_in[2];
    const float* b1   = (const float*)d_in[3];
    const float* W2   = (const float*)d_in[4];
    const float* b2   = (const float*)d_in[5];
    float*       out  = (float*)d_out;

    const int N  = in_sizes[0] / IN_DIM;       // 200000
    const int G  = out_size / POOL_DIM;        // 2000
    const int nb = (N + RPB - 1) / RPB;        // 3125 (<= 3200 padded)

    // workspace layout
    float*  bmax = (float*)d_ws;                        // 3200
    float*  bsum = bmax + 3200;                         // 3200
    float*  red  = bsum + 3200;                         // 16
    int*    meta = (int*)(red + 16);                    // 3200*NSEG ints
    float*  P    = (float*)(meta + 3200 * NSEG);        // 3200*NSEG*4*256 f
    ushort* Wpk  = (ushort*)(P + (size_t)3200 * NSEG * 4 * 256);  // 160 KB

    pack_w1_kernel<<<(NKC * 8 * 2 * 64 + 255) / 256, 256, 0, stream>>>(W1, Wpk);
    attn_fused<<<nb, NT, 0, stream>>>(z, Wpk, b1, W2, b2, bidx,
                                      bmax, bsum, P, meta, N);
    softmax_reduce_kernel<<<1, 256, 0, stream>>>(bmax, bsum, red, nb);
    combine_kernel<<<G, 64, 0, stream>>>(bidx, bmax, red, P, meta, out, N);
}

// Round 14
// 123.800 us; speedup vs baseline: 1.1857x; 1.0987x over previous
//
#include <hip/hip_runtime.h>

#define IN_DIM   320
#define POOL_DIM 256
#define HID      128
#define RPB      128            // rows per block (4 waves x 32 rows)
#define NKC      10             // 320 / 32

typedef __attribute__((ext_vector_type(8))) short bf16x8;
typedef __attribute__((ext_vector_type(4))) float f32x4;

typedef __attribute__((address_space(1))) const unsigned int guint;
typedef __attribute__((address_space(3))) unsigned int luint;

__device__ __forceinline__ void gl_lds16(const void* g, void* l) {
    __builtin_amdgcn_global_load_lds((guint*)g, (luint*)l, 16, 0, 0);
}

__device__ __forceinline__ unsigned fbits(float f) {
    union { float f; unsigned u; } c; c.f = f; return c.u;
}
// pack bf16(trunc) of two f32 bit patterns: low16 = u0>>16, high16 = u1>>16
__device__ __forceinline__ unsigned pack2(unsigned u0, unsigned u1) {
    return __builtin_amdgcn_perm(u1, u0, 0x07060302u);
}

// split 8 f32 into hi(trunc-bf16) + lo(bf16 of residual); hi+lo ~ f32 exact
// to ~2^-16 relative.
__device__ __forceinline__ void split8(float4 a, float4 b, bf16x8& hi, bf16x8& lo) {
    float f[8] = { a.x, a.y, a.z, a.w, b.x, b.y, b.z, b.w };
    unsigned hu[8], lu[8];
#pragma unroll
    for (int i = 0; i < 8; ++i) {
        unsigned u = fbits(f[i]);
        hu[i] = u;
        float hif = __builtin_bit_cast(float, u & 0xffff0000u);
        lu[i] = fbits(f[i] - hif);
    }
    int4 hp, lp;
    hp.x = pack2(hu[0], hu[1]); hp.y = pack2(hu[2], hu[3]);
    hp.z = pack2(hu[4], hu[5]); hp.w = pack2(hu[6], hu[7]);
    lp.x = pack2(lu[0], lu[1]); lp.y = pack2(lu[2], lu[3]);
    lp.z = pack2(lu[4], lu[5]); lp.w = pack2(lu[6], lu[7]);
    hi = __builtin_bit_cast(bf16x8, hp);
    lo = __builtin_bit_cast(bf16x8, lp);
}

// ---------------------------------------------------------------------------
// One-time: pack W1 into MFMA B-fragment order, split hi/lo (frag-linear):
//   Wpk[((kc*16 + ht*2 + s)*64 + lane)*8 + j] =
//       split_s( W1[h = ht*16 + (lane&15)][k = kc*32 + (lane>>4)*8 + j] )
// Frag-linear => the 16KB per-kc chunk can be DMA'd to LDS verbatim.
// ---------------------------------------------------------------------------
__global__ __launch_bounds__(256) void pack_w1_kernel(
    const float* __restrict__ W1, ushort* __restrict__ Wpk)
{
    const int i = blockIdx.x * 256 + threadIdx.x;   // one bf16x8 group each
    if (i >= NKC * 8 * 2 * 64) return;
    const int kc   = i >> 10;
    const int r    = i & 1023;
    const int ht   = r >> 7;
    const int r2   = r & 127;
    const int s    = r2 >> 6;
    const int lane = r2 & 63;
    const int h    = ht * 16 + (lane & 15);
    const int k0   = kc * 32 + (lane >> 4) * 8;

    ushort v[8];
#pragma unroll
    for (int j = 0; j < 8; ++j) {
        const float f = W1[(size_t)h * IN_DIM + k0 + j];
        const unsigned u = fbits(f);
        if (s == 0) {
            v[j] = (ushort)(u >> 16);
        } else {
            const float hif = __builtin_bit_cast(float, u & 0xffff0000u);
            v[j] = (ushort)(fbits(f - hif) >> 16);
        }
    }
    ushort* dst = Wpk + (size_t)i * 8;
#pragma unroll
    for (int j = 0; j < 8; ++j) dst[j] = v[j];
}

// ---------------------------------------------------------------------------
// Kernel A (MFMA, split-bf16, W double-buffered in LDS via global_load_lds,
// z register-prefetch DEPTH 3): per kc: STAGE W[kc+1]->buf^1 (fire-and-forget
// DMA); 16 ds_read b128 W frags; 48 MFMAs; z prefetch kc+3 into the raw
// buffer freed this iter (zraw[kc%3], static after unroll); split z[kc+1].
// mfma_f32_16x16x32_bf16: A row=l&15, k=(l>>4)*8+j; C/D col=l&15,
// row=(l>>4)*4+reg.  3-term split product (drop lo*lo ~ 2^-16 rel).
// ---------------------------------------------------------------------------
__global__ __launch_bounds__(256) void attn_scores_mfma(
    const float* __restrict__ z, const ushort* __restrict__ Wpk,
    const float* __restrict__ b1, const float* __restrict__ W2,
    const float* __restrict__ b2,
    float* __restrict__ scores, float* __restrict__ bmax,
    float* __restrict__ bsum, int N)
{
    __shared__ float4 wbuf[2][1024];   // 2 x 16 KB W-fragment buffers
    __shared__ float  sblk[RPB];

    const int tid  = threadIdx.x;
    const int wid  = tid >> 6;
    const int lane = tid & 63;
    const int lm   = lane & 15;
    const int lg   = lane >> 4;
    const int r0   = blockIdx.x * RPB;
    const int wr0  = r0 + wid * 32;

    int row0 = wr0 + lm;      if (row0 > N - 1) row0 = N - 1;
    int row1 = wr0 + 16 + lm; if (row1 > N - 1) row1 = N - 1;
    const float* zp0 = z + (size_t)row0 * IN_DIM + lg * 8;
    const float* zp1 = z + (size_t)row1 * IN_DIM + lg * 8;

    #define STAGE_W(kc_, b_)                                                  \
        { const char* src = (const char*)Wpk + (size_t)(kc_) * 16384;         \
          char* dst = (char*)&wbuf[b_][0];                                    \
          _Pragma("unroll")                                                   \
          for (int j = 0; j < 4; ++j) {                                       \
              const int o = (tid + j * 256) * 16;                             \
              gl_lds16(src + o, dst + o);                                     \
          } }

    f32x4 acc[2][8];
#pragma unroll
    for (int rt = 0; rt < 2; ++rt)
#pragma unroll
        for (int ht = 0; ht < 8; ++ht) acc[rt][ht] = (f32x4){0.f, 0.f, 0.f, 0.f};

    // z raw TRIPLE-buffer + a-frag double-buffer (statically indexed after
    // full unroll)
    float4 zraw[3][4];
    bf16x8 af[2][4];   // [buf][a0h,a0l,a1h,a1l]

    STAGE_W(0, 0);

    {   // prologue: load z chunks 0,1,2; split z[0]
#pragma unroll
        for (int c = 0; c < 3; ++c) {
            const float4* p0 = (const float4*)(zp0 + c * 32);
            const float4* p1 = (const float4*)(zp1 + c * 32);
            zraw[c][0] = p0[0]; zraw[c][1] = p0[1];
            zraw[c][2] = p1[0]; zraw[c][3] = p1[1];
        }
        split8(zraw[0][0], zraw[0][1], af[0][0], af[0][1]);
        split8(zraw[0][2], zraw[0][3], af[0][2], af[0][3]);
    }
    __syncthreads();   // W[0] staged (compiler inserts vmcnt(0) first)

#pragma unroll
    for (int kc = 0; kc < NKC; ++kc) {
        const int cb  = kc & 1;          // constant after unroll
        const int nb2 = cb ^ 1;

        // issue next W stage early (writes buf^1; its readers finished
        // before the barrier that ended iter kc-1)
        if (kc + 1 < NKC) STAGE_W(kc + 1, nb2);

        // ds_read W frags + MFMAs (A-frags ready since last iter)
        const char* wb_base = (const char*)&wbuf[cb][0] + lane * 16;
#pragma unroll
        for (int ht = 0; ht < 8; ++ht) {
            const bf16x8 bh = *(const bf16x8*)(wb_base + ht * 2048);
            const bf16x8 bl = *(const bf16x8*)(wb_base + ht * 2048 + 1024);
            acc[0][ht] = __builtin_amdgcn_mfma_f32_16x16x32_bf16(af[cb][0], bh, acc[0][ht], 0, 0, 0);
            acc[0][ht] = __builtin_amdgcn_mfma_f32_16x16x32_bf16(af[cb][1], bh, acc[0][ht], 0, 0, 0);
            acc[0][ht] = __builtin_amdgcn_mfma_f32_16x16x32_bf16(af[cb][0], bl, acc[0][ht], 0, 0, 0);
            acc[1][ht] = __builtin_amdgcn_mfma_f32_16x16x32_bf16(af[cb][2], bh, acc[1][ht], 0, 0, 0);
            acc[1][ht] = __builtin_amdgcn_mfma_f32_16x16x32_bf16(af[cb][3], bh, acc[1][ht], 0, 0, 0);
            acc[1][ht] = __builtin_amdgcn_mfma_f32_16x16x32_bf16(af[cb][2], bl, acc[1][ht], 0, 0, 0);
        }

        // z prefetch for kc+3 into the raw buffer freed this iteration
        // (zraw[kc%3] held chunk kc, split at end of iter kc-1)
        if (kc + 3 < NKC) {
            const int ko3 = (kc + 3) * 32;
            const float4* p0 = (const float4*)(zp0 + ko3);
            const float4* p1 = (const float4*)(zp1 + ko3);
            zraw[kc % 3][0] = p0[0]; zraw[kc % 3][1] = p0[1];
            zraw[kc % 3][2] = p1[0]; zraw[kc % 3][3] = p1[1];
        }

        // split z[kc+1] -> frags for next iter
        if (kc + 1 < NKC) {
            const int zn = (kc + 1) % 3;
            split8(zraw[zn][0], zraw[zn][1], af[nb2][0], af[nb2][1]);
            split8(zraw[zn][2], zraw[zn][3], af[nb2][2], af[nb2][3]);
            __syncthreads();   // W[kc+1] staged; buf readers done
        }
    }

    // ---- epilogue: relu + dot(W2) per lane-col, reduce over 16 cols
    float b1v[8], w2v[8];
#pragma unroll
    for (int ht = 0; ht < 8; ++ht) {
        b1v[ht] = b1[ht * 16 + lm];
        w2v[ht] = W2[ht * 16 + lm];
    }
    const float b2v = b2[0];

#pragma unroll
    for (int rt = 0; rt < 2; ++rt) {
#pragma unroll
        for (int reg = 0; reg < 4; ++reg) {
            float s = 0.f;
#pragma unroll
            for (int ht = 0; ht < 8; ++ht)
                s += fmaxf(acc[rt][ht][reg] + b1v[ht], 0.f) * w2v[ht];
            s += __shfl_xor(s, 1);
            s += __shfl_xor(s, 2);
            s += __shfl_xor(s, 4);
            s += __shfl_xor(s, 8);
            s += b2v;
            if (lm == 0) {
                const int rloc = wid * 32 + rt * 16 + lg * 4 + reg;
                const int grow = r0 + rloc;
                if (grow < N) {
                    scores[grow] = s;
                    sblk[rloc] = s;
                } else {
                    sblk[rloc] = -1e30f;
                }
            }
        }
    }
    __syncthreads();

    // ---- block (max, sum-exp): 128 scores folded into one wave
    if (tid < 64) {
        const float v0 = sblk[tid];
        const float v1 = sblk[tid + 64];
        float m = fmaxf(v0, v1);
#pragma unroll
        for (int d = 1; d < 64; d <<= 1) m = fmaxf(m, __shfl_xor(m, d, 64));
        float e = __expf(v0 - m) + __expf(v1 - m);
#pragma unroll
        for (int d = 1; d < 64; d <<= 1) e += __shfl_xor(e, d, 64);
        if (tid == 0) {
            bmax[blockIdx.x] = m;
            bsum[blockIdx.x] = e;
        }
    }
}

// ---------------------------------------------------------------------------
// Kernel E: per-graph weighted mean, float4-vectorized, with the global
// softmax reduction INLINED (each block deterministically reduces
// bmax/bsum -> gmax, den; 12.5 KB L2-resident, ~25 MB aggregate L2 traffic).
// Removes the separate reduce kernel launch + its serialization gap.
// ---------------------------------------------------------------------------
__device__ __forceinline__ int lower_bound(const int* __restrict__ a, int n, int key)
{
    int lo = 0, hi = n;
    while (lo < hi) {
        int mid = (lo + hi) >> 1;
        if (a[mid] < key) lo = mid + 1; else hi = mid;
    }
    return lo;
}

__global__ __launch_bounds__(256) void pool_kernel(
    const float* __restrict__ z, const int* __restrict__ bidx,
    const float* __restrict__ scores, const float* __restrict__ bmax,
    const float* __restrict__ bsum, float* __restrict__ out, int N, int nbk)
{
    const int g    = blockIdx.x;
    const int tid  = threadIdx.x;
    const int lane = tid & 63;           // float4 column
    const int rg   = tid >> 6;           // row-group 0..3
    __shared__ int   se[2];
    __shared__ float sm[4];
    __shared__ float ss[4];
    __shared__ f32x4 pred[4][64];

    // ---- inline global softmax reduce (deterministic per block) ----
    float m = -1e30f;
    for (int i = tid; i < nbk; i += 256) m = fmaxf(m, bmax[i]);
#pragma unroll
    for (int d = 1; d < 64; d <<= 1) m = fmaxf(m, __shfl_xor(m, d, 64));
    if (lane == 0) sm[rg] = m;
    if (tid == 0) {
        se[0] = lower_bound(bidx, N, g);
        se[1] = lower_bound(bidx, N, g + 1);
    }
    __syncthreads();
    const float gmax = fmaxf(fmaxf(sm[0], sm[1]), fmaxf(sm[2], sm[3]));

    float sden = 0.f;
    for (int i = tid; i < nbk; i += 256) sden += bsum[i] * __expf(bmax[i] - gmax);
#pragma unroll
    for (int d = 1; d < 64; d <<= 1) sden += __shfl_xor(sden, d, 64);
    if (lane == 0) ss[rg] = sden;
    __syncthreads();
    const float den = (ss[0] + ss[1]) + (ss[2] + ss[3]);
    const float inv_den = 1.0f / den;

    const int start = se[0], end = se[1];
    const f32x4* zf = (const f32x4*)z;   // 80 f32x4 per row; use first 64

    f32x4 acc = (f32x4){0.f, 0.f, 0.f, 0.f};
    for (int i = start + rg; i < end; i += 4) {
        const float w = __expf(scores[i] - gmax);
        acc += w * zf[(size_t)i * 80 + lane];
    }
    pred[rg][lane] = acc;
    __syncthreads();

    if (rg == 0) {
        const f32x4 s = (pred[0][lane] + pred[1][lane]) +
                        (pred[2][lane] + pred[3][lane]);
        const int cnt = end - start;
        const float sc = inv_den / fmaxf((float)cnt, 1.0f);
        ((f32x4*)out)[(size_t)g * 64 + lane] = s * sc;
    }
}

// ---------------------------------------------------------------------------
extern "C" void kernel_launch(void* const* d_in, const int* in_sizes, int n_in,
                              void* d_out, int out_size, void* d_ws, size_t ws_size,
                              hipStream_t stream)
{
    const float* z    = (const float*)d_in[0];
    const int*   bidx = (const int*)  d_in[1];
    const float* W1   = (const float*)d_in[2];
    const float* b1   = (const float*)d_in[3];
    const float* W2   = (const float*)d_in[4];
    const float* b2   = (const float*)d_in[5];
    float*       out  = (float*)d_out;

    const int N  = in_sizes[0] / IN_DIM;       // 200000
    const int G  = out_size / POOL_DIM;        // 2000
    const int nb = (N + RPB - 1) / RPB;        // 1563 (<= 1600 padded)

    // workspace layout (16B-aligned slots)
    float*  scores = (float*)d_ws;             // N floats
    float*  bmax   = scores + 200000;          // pad region: nb <= 1600
    float*  bsum   = bmax + 1600;
    ushort* Wpk    = (ushort*)(bsum + 1600);   // NKC*8*2*64*8 shorts = 160 KB

    pack_w1_kernel<<<(NKC * 8 * 2 * 64 + 255) / 256, 256, 0, stream>>>(W1, Wpk);
    attn_scores_mfma<<<nb, 256, 0, stream>>>(z, Wpk, b1, W2, b2,
                                             scores, bmax, bsum, N);
    pool_kernel<<<G, 256, 0, stream>>>(z, bidx, scores, bmax, bsum, out, N, nb);
}

// Round 15
// 112.973 us; speedup vs baseline: 1.2993x; 1.0958x over previous
//
#include <hip/hip_runtime.h>

#define IN_DIM   320
#define POOL_DIM 256
#define HID      128
#define RPB      128            // rows per block (4 waves x 32 rows)
#define NKC      10             // 320 / 32

typedef __attribute__((ext_vector_type(8))) short bf16x8;
typedef __attribute__((ext_vector_type(4))) float f32x4;

typedef __attribute__((address_space(1))) const unsigned int guint;
typedef __attribute__((address_space(3))) unsigned int luint;

__device__ __forceinline__ void gl_lds16(const void* g, void* l) {
    __builtin_amdgcn_global_load_lds((guint*)g, (luint*)l, 16, 0, 0);
}

__device__ __forceinline__ unsigned fbits(float f) {
    union { float f; unsigned u; } c; c.f = f; return c.u;
}
// pack bf16(trunc) of two f32 bit patterns: low16 = u0>>16, high16 = u1>>16
__device__ __forceinline__ unsigned pack2(unsigned u0, unsigned u1) {
    return __builtin_amdgcn_perm(u1, u0, 0x07060302u);
}

// split 8 f32 into hi(trunc-bf16) + lo(bf16 of residual); hi+lo ~ f32 exact
// to ~2^-16 relative.
__device__ __forceinline__ void split8(float4 a, float4 b, bf16x8& hi, bf16x8& lo) {
    float f[8] = { a.x, a.y, a.z, a.w, b.x, b.y, b.z, b.w };
    unsigned hu[8], lu[8];
#pragma unroll
    for (int i = 0; i < 8; ++i) {
        unsigned u = fbits(f[i]);
        hu[i] = u;
        float hif = __builtin_bit_cast(float, u & 0xffff0000u);
        lu[i] = fbits(f[i] - hif);
    }
    int4 hp, lp;
    hp.x = pack2(hu[0], hu[1]); hp.y = pack2(hu[2], hu[3]);
    hp.z = pack2(hu[4], hu[5]); hp.w = pack2(hu[6], hu[7]);
    lp.x = pack2(lu[0], lu[1]); lp.y = pack2(lu[2], lu[3]);
    lp.z = pack2(lu[4], lu[5]); lp.w = pack2(lu[6], lu[7]);
    hi = __builtin_bit_cast(bf16x8, hp);
    lo = __builtin_bit_cast(bf16x8, lp);
}

// ---------------------------------------------------------------------------
// One-time: pack W1 into MFMA B-fragment order, split hi/lo (frag-linear):
//   Wpk[((kc*16 + ht*2 + s)*64 + lane)*8 + j] =
//       split_s( W1[h = ht*16 + (lane&15)][k = kc*32 + (lane>>4)*8 + j] )
// Frag-linear => the 16KB per-kc chunk can be DMA'd to LDS verbatim.
// ---------------------------------------------------------------------------
__global__ __launch_bounds__(256) void pack_w1_kernel(
    const float* __restrict__ W1, ushort* __restrict__ Wpk)
{
    const int i = blockIdx.x * 256 + threadIdx.x;   // one bf16x8 group each
    if (i >= NKC * 8 * 2 * 64) return;
    const int kc   = i >> 10;
    const int r    = i & 1023;
    const int ht   = r >> 7;
    const int r2   = r & 127;
    const int s    = r2 >> 6;
    const int lane = r2 & 63;
    const int h    = ht * 16 + (lane & 15);
    const int k0   = kc * 32 + (lane >> 4) * 8;

    ushort v[8];
#pragma unroll
    for (int j = 0; j < 8; ++j) {
        const float f = W1[(size_t)h * IN_DIM + k0 + j];
        const unsigned u = fbits(f);
        if (s == 0) {
            v[j] = (ushort)(u >> 16);
        } else {
            const float hif = __builtin_bit_cast(float, u & 0xffff0000u);
            v[j] = (ushort)(fbits(f - hif) >> 16);
        }
    }
    ushort* dst = Wpk + (size_t)i * 8;
#pragma unroll
    for (int j = 0; j < 8; ++j) dst[j] = v[j];
}

// ---------------------------------------------------------------------------
// Kernel A (MFMA, split-bf16, W double-buffered in LDS via global_load_lds):
// per kc: STAGE W[kc+1]->buf^1 (fire-and-forget DMA); ds_read 16 W frags;
// 48 MFMAs; z direct-prefetch depth 2; one barrier per kc.
// (Round-7 structure exactly — measured best at 110.4 us total.)
// mfma_f32_16x16x32_bf16: A row=l&15, k=(l>>4)*8+j; C/D col=l&15,
// row=(l>>4)*4+reg.  3-term split product (drop lo*lo ~ 2^-16 rel).
// ---------------------------------------------------------------------------
__global__ __launch_bounds__(256) void attn_scores_mfma(
    const float* __restrict__ z, const ushort* __restrict__ Wpk,
    const float* __restrict__ b1, const float* __restrict__ W2,
    const float* __restrict__ b2,
    float* __restrict__ scores, float* __restrict__ bmax,
    float* __restrict__ bsum, int N)
{
    __shared__ float4 wbuf[2][1024];   // 2 x 16 KB W-fragment buffers
    __shared__ float  sblk[RPB];

    const int tid  = threadIdx.x;
    const int wid  = tid >> 6;
    const int lane = tid & 63;
    const int lm   = lane & 15;
    const int lg   = lane >> 4;
    const int r0   = blockIdx.x * RPB;
    const int wr0  = r0 + wid * 32;

    int row0 = wr0 + lm;      if (row0 > N - 1) row0 = N - 1;
    int row1 = wr0 + 16 + lm; if (row1 > N - 1) row1 = N - 1;
    const float* zp0 = z + (size_t)row0 * IN_DIM + lg * 8;
    const float* zp1 = z + (size_t)row1 * IN_DIM + lg * 8;

    #define STAGE_W(kc_, b_)                                                  \
        { const char* src = (const char*)Wpk + (size_t)(kc_) * 16384;         \
          char* dst = (char*)&wbuf[b_][0];                                    \
          _Pragma("unroll")                                                   \
          for (int j = 0; j < 4; ++j) {                                       \
              const int o = (tid + j * 256) * 16;                             \
              gl_lds16(src + o, dst + o);                                     \
          } }

    f32x4 acc[2][8];
#pragma unroll
    for (int rt = 0; rt < 2; ++rt)
#pragma unroll
        for (int ht = 0; ht < 8; ++ht) acc[rt][ht] = (f32x4){0.f, 0.f, 0.f, 0.f};

    // z raw double-buffer + a-frag double-buffer (statically indexed after
    // full unroll)
    float4 zraw[2][4];
    bf16x8 af[2][4];   // [buf][a0h,a0l,a1h,a1l]

    STAGE_W(0, 0);

    {   // prologue: load z[0], z[1]; split z[0]
        const float4* p0 = (const float4*)zp0;
        const float4* p1 = (const float4*)zp1;
        zraw[0][0] = p0[0]; zraw[0][1] = p0[1];
        zraw[0][2] = p1[0]; zraw[0][3] = p1[1];
        const float4* q0 = (const float4*)(zp0 + 32);
        const float4* q1 = (const float4*)(zp1 + 32);
        zraw[1][0] = q0[0]; zraw[1][1] = q0[1];
        zraw[1][2] = q1[0]; zraw[1][3] = q1[1];
        split8(zraw[0][0], zraw[0][1], af[0][0], af[0][1]);
        split8(zraw[0][2], zraw[0][3], af[0][2], af[0][3]);
    }
    __syncthreads();   // W[0] staged (compiler inserts vmcnt(0) first)

#pragma unroll
    for (int kc = 0; kc < NKC; ++kc) {
        const int cb  = kc & 1;          // constant after unroll
        const int nb2 = cb ^ 1;

        // issue next W stage early (writes buf^1; its readers finished
        // before the barrier that ended iter kc-1)
        if (kc + 1 < NKC) STAGE_W(kc + 1, nb2);

        // ds_read W frags + MFMAs (A-frags ready since last iter)
        const char* wb_base = (const char*)&wbuf[cb][0] + lane * 16;
#pragma unroll
        for (int ht = 0; ht < 8; ++ht) {
            const bf16x8 bh = *(const bf16x8*)(wb_base + ht * 2048);
            const bf16x8 bl = *(const bf16x8*)(wb_base + ht * 2048 + 1024);
            acc[0][ht] = __builtin_amdgcn_mfma_f32_16x16x32_bf16(af[cb][0], bh, acc[0][ht], 0, 0, 0);
            acc[0][ht] = __builtin_amdgcn_mfma_f32_16x16x32_bf16(af[cb][1], bh, acc[0][ht], 0, 0, 0);
            acc[0][ht] = __builtin_amdgcn_mfma_f32_16x16x32_bf16(af[cb][0], bl, acc[0][ht], 0, 0, 0);
            acc[1][ht] = __builtin_amdgcn_mfma_f32_16x16x32_bf16(af[cb][2], bh, acc[1][ht], 0, 0, 0);
            acc[1][ht] = __builtin_amdgcn_mfma_f32_16x16x32_bf16(af[cb][3], bh, acc[1][ht], 0, 0, 0);
            acc[1][ht] = __builtin_amdgcn_mfma_f32_16x16x32_bf16(af[cb][2], bl, acc[1][ht], 0, 0, 0);
        }

        // z prefetch for kc+2 (overwrites raw buffer already split)
        if (kc + 2 < NKC) {
            const int ko2 = (kc + 2) * 32;
            const float4* p0 = (const float4*)(zp0 + ko2);
            const float4* p1 = (const float4*)(zp1 + ko2);
            zraw[cb][0] = p0[0]; zraw[cb][1] = p0[1];
            zraw[cb][2] = p1[0]; zraw[cb][3] = p1[1];
        }

        // split z[kc+1] -> frags for next iter
        if (kc + 1 < NKC) {
            split8(zraw[nb2][0], zraw[nb2][1], af[nb2][0], af[nb2][1]);
            split8(zraw[nb2][2], zraw[nb2][3], af[nb2][2], af[nb2][3]);
            __syncthreads();   // W[kc+1] staged; buf readers done
        }
    }

    // ---- epilogue: relu + dot(W2) per lane-col, reduce over 16 cols
    float b1v[8], w2v[8];
#pragma unroll
    for (int ht = 0; ht < 8; ++ht) {
        b1v[ht] = b1[ht * 16 + lm];
        w2v[ht] = W2[ht * 16 + lm];
    }
    const float b2v = b2[0];

#pragma unroll
    for (int rt = 0; rt < 2; ++rt) {
#pragma unroll
        for (int reg = 0; reg < 4; ++reg) {
            float s = 0.f;
#pragma unroll
            for (int ht = 0; ht < 8; ++ht)
                s += fmaxf(acc[rt][ht][reg] + b1v[ht], 0.f) * w2v[ht];
            s += __shfl_xor(s, 1);
            s += __shfl_xor(s, 2);
            s += __shfl_xor(s, 4);
            s += __shfl_xor(s, 8);
            s += b2v;
            if (lm == 0) {
                const int rloc = wid * 32 + rt * 16 + lg * 4 + reg;
                const int grow = r0 + rloc;
                if (grow < N) {
                    scores[grow] = s;
                    sblk[rloc] = s;
                } else {
                    sblk[rloc] = -1e30f;
                }
            }
        }
    }
    __syncthreads();

    // ---- block (max, sum-exp): 128 scores folded into one wave
    if (tid < 64) {
        const float v0 = sblk[tid];
        const float v1 = sblk[tid + 64];
        float m = fmaxf(v0, v1);
#pragma unroll
        for (int d = 1; d < 64; d <<= 1) m = fmaxf(m, __shfl_xor(m, d, 64));
        float e = __expf(v0 - m) + __expf(v1 - m);
#pragma unroll
        for (int d = 1; d < 64; d <<= 1) e += __shfl_xor(e, d, 64);
        if (tid == 0) {
            bmax[blockIdx.x] = m;
            bsum[blockIdx.x] = e;
        }
    }
}

// ---------------------------------------------------------------------------
// Kernel B: combine per-block (max, sumexp) -> global max & softmax denom
// ---------------------------------------------------------------------------
__global__ __launch_bounds__(256) void softmax_reduce_kernel(
    const float* __restrict__ bmax, const float* __restrict__ bsum,
    float* __restrict__ red, int nb)
{
    __shared__ float sm[4];
    __shared__ float ss[4];
    const int tid = threadIdx.x;

    float m = -1e30f;
    for (int i = tid; i < nb; i += 256) m = fmaxf(m, bmax[i]);
#pragma unroll
    for (int d = 1; d < 64; d <<= 1) m = fmaxf(m, __shfl_xor(m, d, 64));
    if ((tid & 63) == 0) sm[tid >> 6] = m;
    __syncthreads();
    const float gmax = fmaxf(fmaxf(sm[0], sm[1]), fmaxf(sm[2], sm[3]));

    float s = 0.f;
    for (int i = tid; i < nb; i += 256) s += bsum[i] * __expf(bmax[i] - gmax);
#pragma unroll
    for (int d = 1; d < 64; d <<= 1) s += __shfl_xor(s, d, 64);
    if ((tid & 63) == 0) ss[tid >> 6] = s;
    __syncthreads();
    if (tid == 0) {
        red[0] = gmax;
        red[1] = ss[0] + ss[1] + ss[2] + ss[3];
    }
}

// ---------------------------------------------------------------------------
// Kernel E: per-graph weighted mean, float4-vectorized.
// Block = 256 threads = 4 row-groups x 64 float4-lanes (256 cols).
// REVERSED graph order (g = G-1-blockIdx): pool consumes z back-to-front,
// starting where attn just finished -> tail of z is L3-hot; symmetrically
// leaves z's front hot for the next replay's attn. Per-block math identical.
// ---------------------------------------------------------------------------
__device__ __forceinline__ int lower_bound(const int* __restrict__ a, int n, int key)
{
    int lo = 0, hi = n;
    while (lo < hi) {
        int mid = (lo + hi) >> 1;
        if (a[mid] < key) lo = mid + 1; else hi = mid;
    }
    return lo;
}

__global__ __launch_bounds__(256) void pool_kernel(
    const float* __restrict__ z, const int* __restrict__ bidx,
    const float* __restrict__ scores, const float* __restrict__ red,
    float* __restrict__ out, int N)
{
    const int g    = gridDim.x - 1 - blockIdx.x;   // reversed for L3 reuse
    const int lane = threadIdx.x & 63;   // float4 column
    const int rg   = threadIdx.x >> 6;   // row-group 0..3
    __shared__ int se[2];
    __shared__ f32x4 pred[4][64];

    if (threadIdx.x == 0) {
        se[0] = lower_bound(bidx, N, g);
        se[1] = lower_bound(bidx, N, g + 1);
    }
    __syncthreads();
    const int start = se[0], end = se[1];
    const float gmax    = red[0];
    const float inv_den = 1.0f / red[1];

    const f32x4* zf = (const f32x4*)z;   // 80 f32x4 per row; use first 64

    f32x4 acc = (f32x4){0.f, 0.f, 0.f, 0.f};
    for (int i = start + rg; i < end; i += 4) {
        const float w = __expf(scores[i] - gmax);
        acc += w * zf[(size_t)i * 80 + lane];
    }
    pred[rg][lane] = acc;
    __syncthreads();

    if (rg == 0) {
        const f32x4 s = (pred[0][lane] + pred[1][lane]) +
                        (pred[2][lane] + pred[3][lane]);
        const int cnt = end - start;
        const float sc = inv_den / fmaxf((float)cnt, 1.0f);
        ((f32x4*)out)[(size_t)g * 64 + lane] = s * sc;
    }
}

// ---------------------------------------------------------------------------
extern "C" void kernel_launch(void* const* d_in, const int* in_sizes, int n_in,
                              void* d_out, int out_size, void* d_ws, size_t ws_size,
                              hipStream_t stream)
{
    const float* z    = (const float*)d_in[0];
    const int*   bidx = (const int*)  d_in[1];
    const float* W1   = (const float*)d_in[2];
    const float* b1   = (const float*)d_in[3];
    const float* W2   = (const float*)d_in[4];
    const float* b2   = (const float*)d_in[5];
    float*       out  = (float*)d_out;

    const int N  = in_sizes[0] / IN_DIM;       // 200000
    const int G  = out_size / POOL_DIM;        // 2000
    const int nb = (N + RPB - 1) / RPB;        // 1563 (<= 1600 padded)

    // workspace layout (16B-aligned slots)
    float*  scores = (float*)d_ws;             // N floats
    float*  bmax   = scores + 200000;          // pad region: nb <= 1600
    float*  bsum   = bmax + 1600;
    float*  red    = bsum + 1600;
    ushort* Wpk    = (ushort*)(red + 16);      // NKC*8*2*64*8 shorts = 160 KB

    pack_w1_kernel<<<(NKC * 8 * 2 * 64 + 255) / 256, 256, 0, stream>>>(W1, Wpk);
    attn_scores_mfma<<<nb, 256, 0, stream>>>(z, Wpk, b1, W2, b2,
                                             scores, bmax, bsum, N);
    softmax_reduce_kernel<<<1, 256, 0, stream>>>(bmax, bsum, red, nb);
    pool_kernel<<<G, 256, 0, stream>>>(z, bidx, scores, red, out, N);
}